// Round 18
// baseline (232.276 us; speedup 1.0000x reference)
//
#include <hip/hip_runtime.h>

#define IH 126
#define IW 126
#define HW 15876      // 126*126
#define OH 124
#define OW 124
#define OHW 15376     // 124*124

// Activations between kernels are HWC: a[(y*IW+x)*64 + c] (r6 win: 256 B runs).

// ---------------------------------------------------------------- conv_in (HWC out)
__global__ __launch_bounds__(256) void conv_in_kernel(
    const float* __restrict__ x, const float* __restrict__ w,
    const float* __restrict__ b, float* __restrict__ y)
{
  int tid = threadIdx.x;
  int oc = tid & 63;
  int w_ = __builtin_amdgcn_readfirstlane(tid >> 6);   // wave 0..3
  int pix = blockIdx.x * 4 + w_;
  if (pix >= HW) return;
  int h  = pix / IW;
  int wc = pix - h * IW;
  const float* wp = w + oc * 27;
  float acc = b[oc];
#pragma unroll
  for (int ci = 0; ci < 3; ci++)
#pragma unroll
    for (int ky = 0; ky < 3; ky++)
#pragma unroll
      for (int kx = 0; kx < 3; kx++)
        acc = fmaf(x[ci * 128 * 128 + (h + ky) * 128 + (wc + kx)],   // uniform
                   wp[ci * 9 + ky * 3 + kx], acc);
  y[pix * 64 + oc] = acc;
}

#define XSW(c, pos) ((c) ^ (((pos) & 7) << 3))
#define WVP4 36

// ---------------------------------------------------------------- involution v13 (BEST MEASURED — FROZEN)
// 30.5 +/- 1 us/layer across 7 structural variants; minimal-work phases;
// s_load broadcast weights beat LDS staging (3x confirmed). Do not touch.
__global__ __launch_bounds__(512, 4) void inv_kernel(
    const float* __restrict__ x, float* __restrict__ y,
    const float* __restrict__ wr, const float* __restrict__ br,
    const float* __restrict__ gam, const float* __restrict__ bet,
    const float* __restrict__ mu, const float* __restrict__ var,
    const float* __restrict__ wspan, const float* __restrict__ bspan)
{
  __shared__ __align__(16) float xs[140][68];    // 38,080 B
  __shared__ __align__(16) float wvs[196 * WVP4];// 28,224 B
  __shared__ __align__(16) float tss[640];       // 2,560 B; [32 px][20]
  __shared__ __align__(16) float wrs[1024];      // 4,096 B; staged Wr [16][64]

  int tid = threadIdx.x;
  int bx = blockIdx.x & 15, by = blockIdx.x >> 4;
  int ox0 = bx * 8, oy0 = by * 4;
  int xh0 = ox0 - 3, yh0 = oy0 - 3;

  // ---- Phase A: stage x halo (14 x 10 x 64 ch) from HWC + Wr into LDS
  for (int idx = tid; idx < 140 * 16; idx += 512) {
    int pos = idx >> 4;
    int c4  = (idx & 15) << 2;
    int row = pos / 14;
    int col = pos - row * 14;
    int gy = yh0 + row, gx = xh0 + col;
    float4 v = make_float4(0.f, 0.f, 0.f, 0.f);
    if (gy >= 0 && gy < IH && gx >= 0 && gx < IW)
      v = *(const float4*)&x[(gy * IW + gx) * 64 + c4];
    *(float4*)&xs[pos][XSW(c4, pos)] = v;
  }
  for (int j = tid; j < 1024; j += 512) wrs[j] = wr[j];
  __syncthreads();

  int w_ = __builtin_amdgcn_readfirstlane(tid >> 6);  // wave 0..7
  int ln = tid & 63;
  int p  = ln & 31;                   // pixel 0..31
  int prow = p >> 3, pcol = p & 7;
  int pc = (prow + 3) * 14 + (pcol + 3);

  // ---- Phase B: t = ReLU(BN(Wr.x)); lane = (pixel, half): cr = 2w_+(ln>>5)
  {
    int cr = 2 * w_ + (ln >> 5);
    const float* wa = &wrs[cr * 64];   // 2 addrs/wave -> broadcast, free
    float a = 0.f;
    int xsw = (pc & 7) << 3;
#pragma unroll
    for (int ci = 0; ci < 64; ci += 4) {
      int cis = ci ^ xsw;             // quad-aligned: b128-able; <=2-way banks
      float4 xv = *(const float4*)&xs[pc][cis];
      float4 av = *(const float4*)&wa[cis];
      a = fmaf(xv.x, av.x, a);
      a = fmaf(xv.y, av.y, a);
      a = fmaf(xv.z, av.z, a);
      a = fmaf(xv.w, av.w, a);
    }
    float s = gam[cr] * rsqrtf(var[cr] + 1e-5f);
    float t = (a + br[cr] - mu[cr]) * s + bet[cr];
    tss[p * 20 + cr] = fmaxf(t, 0.f);  // all 64 lanes; exact coverage
  }
  __syncthreads();

  // ---- Phase C: span. s_load weight batches; results in regs; writes deferred
  {
    float tv[16];
#pragma unroll
    for (int i = 0; i < 4; i++) {
      float4 t4 = *(const float4*)&tss[p * 20 + 4 * i];
      tv[4 * i] = t4.x; tv[4 * i + 1] = t4.y;
      tv[4 * i + 2] = t4.z; tv[4 * i + 3] = t4.w;
    }
    float wv[25];
#pragma unroll
    for (int j = 0; j < 25; j++) {
      int pair = w_ + 8 * j;           // wave-uniform
      float a = 0.f;
      if (pair < 196) {
        const float* wk = wspan + pair * 16;   // uniform -> s_load_dwordx16
        a = bspan[pair];
#pragma unroll
        for (int i = 0; i < 16; i++) a = fmaf(tv[i], wk[i], a);
      }
      wv[j] = a;
    }
    if (ln < 32) {
#pragma unroll
      for (int j = 0; j < 25; j++) {
        int pair = w_ + 8 * j;
        if (pair < 196) wvs[pair * WVP4 + pcol * 4 + prow] = wv[j];
      }
    }
  }
  __syncthreads();

  // ---- Phase D: einsum. wave = output column w_, lane = channel. (all-LDS)
  float acc0 = 0.f, acc1 = 0.f, acc2 = 0.f, acc3 = 0.f;
  {
    int c = ln;
    int g = ln >> 4;
    float xw[4][7];
#pragma unroll
    for (int r = 0; r < 4; r++)
#pragma unroll
      for (int kx = 0; kx < 7; kx++) {
        int pos = r * 14 + w_ + kx;
        xw[r][kx] = xs[pos][XSW(c, pos)];
      }
#pragma unroll
    for (int ky = 0; ky < 7; ky++) {
      if (ky > 0) {
#pragma unroll
        for (int r = 0; r < 3; r++)
#pragma unroll
          for (int kx = 0; kx < 7; kx++) xw[r][kx] = xw[r + 1][kx];
#pragma unroll
        for (int kx = 0; kx < 7; kx++) {
          int pos = (ky + 3) * 14 + w_ + kx;
          xw[3][kx] = xs[pos][XSW(c, pos)];
        }
      }
#pragma unroll
      for (int kx = 0; kx < 7; kx++) {
        int k = ky * 7 + kx;
        float4 w4 = *(const float4*)&wvs[(g * 49 + k) * WVP4 + w_ * 4];
        acc0 = fmaf(w4.x, xw[0][kx], acc0);
        acc1 = fmaf(w4.y, xw[1][kx], acc1);
        acc2 = fmaf(w4.z, xw[2][kx], acc2);
        acc3 = fmaf(w4.w, xw[3][kx], acc3);
      }
    }
  }

  // ---- direct HWC store (outer ReLU fused)
  {
    int c = ln;
    int gx = ox0 + w_;
    if (gx < IW) {
      int base = (oy0 * IW + gx) * 64 + c;
      y[base]               = fmaxf(acc0, 0.f);
      y[base + 1 * IW * 64] = fmaxf(acc1, 0.f);
      if (oy0 + 2 < IH) y[base + 2 * IW * 64] = fmaxf(acc2, 0.f);
      if (oy0 + 3 < IH) y[base + 3 * IW * 64] = fmaxf(acc3, 0.f);
    }
  }
}

// ---------------------------------------------------------------- conv_out prep
// v9 layout: [k][grp4][wv4][cq16][ci4][oc8] — each (tap, wave) slab is 512
// CONTIGUOUS floats, so the inner loop's s_loads are base + immediate offsets
// (one base per tap instead of per-iteration strided address arithmetic).
__global__ __launch_bounds__(256) void transpose_w_kernel(
    const float* __restrict__ w, float* __restrict__ wt)
{
  int i = blockIdx.x * 256 + threadIdx.x;
  if (i >= 128 * 64 * 9) return;
  int oc = i / 576;
  int rem = i - oc * 576;
  int ci = rem / 9;
  int k = rem - ci * 9;
  int grp = oc >> 5, wv = (oc >> 3) & 3, oc8 = oc & 7;
  int cq = ci >> 2, ci4 = ci & 3;
  wt[(((k * 16 + grp * 4 + wv) * 16 + cq) * 4 + ci4) * 8 + oc8] = w[i];
}

// ---------------------------------------------------------------- conv_out v9
// = v3 byte-identical structure; ONLY the weight layout changed (see
// transpose_w): per (tap, wave) the 512 weight floats are contiguous ->
// all 16 cq batches are s_load_dwordx16 at base+imm off ONE base per tap.
// Targets the ~25 us SMEM-chain stall (VALU 15.4, LDS ~3 of the 43 us).
__global__ __launch_bounds__(256, 6) void conv_out_kernel(
    const float* __restrict__ x, const float* __restrict__ wt,
    const float* __restrict__ b, float* __restrict__ y)
{
  __shared__ __align__(16) float xsm[16 * 100 * 4];   // 25,600 B
  int tid = threadIdx.x;
  int bx = blockIdx.x & 15, by = blockIdx.x >> 4;
  int oy0 = by * 8, ox0 = bx * 8;

  for (int u = tid; u < 1600; u += 256) {
    int cq = u / 100;
    int pos = u - cq * 100;
    int row = pos / 10;
    int col = pos - row * 10;
    int gy = oy0 + row, gx = ox0 + col;
    float4 v = make_float4(0.f, 0.f, 0.f, 0.f);
    if (gy < IH && gx < IW)
      v = *(const float4*)&x[(gy * IW + gx) * 64 + cq * 4];
    *(float4*)&xsm[u * 4] = v;
  }
  __syncthreads();

  int ln = tid & 63;
  int px = ln & 7, py = ln >> 3;
  int wv_ = __builtin_amdgcn_readfirstlane(tid >> 6);   // wave 0..3
  int oc8 = blockIdx.y * 32 + wv_ * 8;

  float acc[8];
#pragma unroll
  for (int j = 0; j < 8; j++) acc[j] = b[oc8 + j];

#pragma unroll
  for (int ky = 0; ky < 3; ky++) {
#pragma unroll
    for (int kx = 0; kx < 3; kx++) {
      int k = ky * 3 + kx;
      int pidx = (py + ky) * 10 + px + kx;
      // ONE uniform base per (tap, wave): 512 contiguous floats
      const float* wp = wt + (k * 16 + blockIdx.y * 4 + wv_) * 512;
#pragma unroll 4
      for (int cq = 0; cq < 16; cq++) {
        float4 xv = *(const float4*)&xsm[(cq * 100 + pidx) * 4];
        const float* wq = wp + cq * 32;         // imm offset: cq*128 B
#pragma unroll
        for (int j = 0; j < 8; j++) {
          acc[j] = fmaf(xv.x, wq[0 * 8 + j], acc[j]);
          acc[j] = fmaf(xv.y, wq[1 * 8 + j], acc[j]);
          acc[j] = fmaf(xv.z, wq[2 * 8 + j], acc[j]);
          acc[j] = fmaf(xv.w, wq[3 * 8 + j], acc[j]);
        }
      }
    }
  }

  int oy = oy0 + py, ox = ox0 + px;
  if (oy < OH && ox < OW) {
#pragma unroll
    for (int j = 0; j < 8; j++)
      y[(oc8 + j) * OHW + oy * OW + ox] = acc[j];
  }
}

// ---------------------------------------------------------------- launch
extern "C" void kernel_launch(void* const* d_in, const int* in_sizes, int n_in,
                              void* d_out, int out_size, void* d_ws, size_t ws_size,
                              hipStream_t stream)
{
  const float* input = (const float*)d_in[0];
  const float* ciw   = (const float*)d_in[1];
  const float* cib   = (const float*)d_in[2];
  const float* wred  = (const float*)d_in[3];
  const float* bred  = (const float*)d_in[4];
  const float* gam   = (const float*)d_in[5];
  const float* bet   = (const float*)d_in[6];
  const float* mu    = (const float*)d_in[7];
  const float* var   = (const float*)d_in[8];
  const float* wspan = (const float*)d_in[9];
  const float* bspan = (const float*)d_in[10];
  const float* cow   = (const float*)d_in[11];
  const float* cob   = (const float*)d_in[12];
  float* out = (float*)d_out;

  float* bufA = (float*)d_ws;                 // HWC: 15876*64 = 1,016,064 floats
  float* bufB = bufA + (1 << 20);             // @ 4 MiB
  float* wt   = bufA + (1 << 21);             // @ 8 MiB, 73,728 floats

  transpose_w_kernel<<<288, 256, 0, stream>>>(cow, wt);
  conv_in_kernel<<<3969, 256, 0, stream>>>(input, ciw, cib, bufA);

  float* cur = bufA; float* nxt = bufB;
  for (int i = 0; i < 6; i++) {
    inv_kernel<<<512, 512, 0, stream>>>(cur, nxt,
        wred + i * 16 * 64, bred + i * 16, gam + i * 16, bet + i * 16,
        mu + i * 16, var + i * 16, wspan + i * 196 * 16, bspan + i * 196);
    float* t = cur; cur = nxt; nxt = t;
  }
  conv_out_kernel<<<dim3(256, 4), 256, 0, stream>>>(cur, wt, cob, out);
}

// Round 19
// 230.841 us; speedup vs baseline: 1.0062x; 1.0062x over previous
//
#include <hip/hip_runtime.h>

#define IH 126
#define IW 126
#define HW 15876      // 126*126
#define OH 124
#define OW 124
#define OHW 15376     // 124*124

// Activations between kernels are HWC: a[(y*IW+x)*64 + c] (r6 win: 256 B runs).

// ---------------------------------------------------------------- conv_in prep
// ciw [64oc][3ci][3][3] -> wt2 [27k][64oc]: per-tap weight reads coalesce.
__global__ __launch_bounds__(256) void transpose_ci_kernel(
    const float* __restrict__ w, float* __restrict__ wt2)
{
  int i = blockIdx.x * 256 + threadIdx.x;
  if (i >= 64 * 27) return;
  int oc = i / 27;
  int kk = i - oc * 27;
  wt2[kk * 64 + oc] = w[i];
}

// ---------------------------------------------------------------- conv_in v2 (HWC out)
// wave = pixel (uniform x taps -> s_load), lane = oc. v2: weights via
// wt2[k][64] -> 27 COALESCED 256B loads (was stride-108B gather, ~54
// lines/wave-inst). Store unchanged (256B contiguous HWC).
__global__ __launch_bounds__(256) void conv_in_kernel(
    const float* __restrict__ x, const float* __restrict__ wt2,
    const float* __restrict__ b, float* __restrict__ y)
{
  int tid = threadIdx.x;
  int oc = tid & 63;
  int w_ = __builtin_amdgcn_readfirstlane(tid >> 6);   // wave 0..3
  int pix = blockIdx.x * 4 + w_;
  if (pix >= HW) return;
  int h  = pix / IW;
  int wc = pix - h * IW;
  float acc = b[oc];
#pragma unroll
  for (int ci = 0; ci < 3; ci++)
#pragma unroll
    for (int ky = 0; ky < 3; ky++)
#pragma unroll
      for (int kx = 0; kx < 3; kx++)
        acc = fmaf(x[ci * 128 * 128 + (h + ky) * 128 + (wc + kx)],   // uniform
                   wt2[(ci * 9 + ky * 3 + kx) * 64 + oc], acc);      // coalesced
  y[pix * 64 + oc] = acc;
}

#define XSW(c, pos) ((c) ^ (((pos) & 7) << 3))
#define WVP4 36

// ---------------------------------------------------------------- involution v13 (BEST MEASURED — FROZEN)
// 30.5 +/- 1 us/layer across 7 structural variants; minimal-work phases;
// s_load broadcast weights beat LDS staging (3x confirmed). Do not touch.
__global__ __launch_bounds__(512, 4) void inv_kernel(
    const float* __restrict__ x, float* __restrict__ y,
    const float* __restrict__ wr, const float* __restrict__ br,
    const float* __restrict__ gam, const float* __restrict__ bet,
    const float* __restrict__ mu, const float* __restrict__ var,
    const float* __restrict__ wspan, const float* __restrict__ bspan)
{
  __shared__ __align__(16) float xs[140][68];    // 38,080 B
  __shared__ __align__(16) float wvs[196 * WVP4];// 28,224 B
  __shared__ __align__(16) float tss[640];       // 2,560 B; [32 px][20]
  __shared__ __align__(16) float wrs[1024];      // 4,096 B; staged Wr [16][64]

  int tid = threadIdx.x;
  int bx = blockIdx.x & 15, by = blockIdx.x >> 4;
  int ox0 = bx * 8, oy0 = by * 4;
  int xh0 = ox0 - 3, yh0 = oy0 - 3;

  // ---- Phase A: stage x halo (14 x 10 x 64 ch) from HWC + Wr into LDS
  for (int idx = tid; idx < 140 * 16; idx += 512) {
    int pos = idx >> 4;
    int c4  = (idx & 15) << 2;
    int row = pos / 14;
    int col = pos - row * 14;
    int gy = yh0 + row, gx = xh0 + col;
    float4 v = make_float4(0.f, 0.f, 0.f, 0.f);
    if (gy >= 0 && gy < IH && gx >= 0 && gx < IW)
      v = *(const float4*)&x[(gy * IW + gx) * 64 + c4];
    *(float4*)&xs[pos][XSW(c4, pos)] = v;
  }
  for (int j = tid; j < 1024; j += 512) wrs[j] = wr[j];
  __syncthreads();

  int w_ = __builtin_amdgcn_readfirstlane(tid >> 6);  // wave 0..7
  int ln = tid & 63;
  int p  = ln & 31;                   // pixel 0..31
  int prow = p >> 3, pcol = p & 7;
  int pc = (prow + 3) * 14 + (pcol + 3);

  // ---- Phase B: t = ReLU(BN(Wr.x)); lane = (pixel, half): cr = 2w_+(ln>>5)
  {
    int cr = 2 * w_ + (ln >> 5);
    const float* wa = &wrs[cr * 64];   // 2 addrs/wave -> broadcast, free
    float a = 0.f;
    int xsw = (pc & 7) << 3;
#pragma unroll
    for (int ci = 0; ci < 64; ci += 4) {
      int cis = ci ^ xsw;             // quad-aligned: b128-able; <=2-way banks
      float4 xv = *(const float4*)&xs[pc][cis];
      float4 av = *(const float4*)&wa[cis];
      a = fmaf(xv.x, av.x, a);
      a = fmaf(xv.y, av.y, a);
      a = fmaf(xv.z, av.z, a);
      a = fmaf(xv.w, av.w, a);
    }
    float s = gam[cr] * rsqrtf(var[cr] + 1e-5f);
    float t = (a + br[cr] - mu[cr]) * s + bet[cr];
    tss[p * 20 + cr] = fmaxf(t, 0.f);  // all 64 lanes; exact coverage
  }
  __syncthreads();

  // ---- Phase C: span. s_load weight batches; results in regs; writes deferred
  {
    float tv[16];
#pragma unroll
    for (int i = 0; i < 4; i++) {
      float4 t4 = *(const float4*)&tss[p * 20 + 4 * i];
      tv[4 * i] = t4.x; tv[4 * i + 1] = t4.y;
      tv[4 * i + 2] = t4.z; tv[4 * i + 3] = t4.w;
    }
    float wv[25];
#pragma unroll
    for (int j = 0; j < 25; j++) {
      int pair = w_ + 8 * j;           // wave-uniform
      float a = 0.f;
      if (pair < 196) {
        const float* wk = wspan + pair * 16;   // uniform -> s_load_dwordx16
        a = bspan[pair];
#pragma unroll
        for (int i = 0; i < 16; i++) a = fmaf(tv[i], wk[i], a);
      }
      wv[j] = a;
    }
    if (ln < 32) {
#pragma unroll
      for (int j = 0; j < 25; j++) {
        int pair = w_ + 8 * j;
        if (pair < 196) wvs[pair * WVP4 + pcol * 4 + prow] = wv[j];
      }
    }
  }
  __syncthreads();

  // ---- Phase D: einsum. wave = output column w_, lane = channel. (all-LDS)
  float acc0 = 0.f, acc1 = 0.f, acc2 = 0.f, acc3 = 0.f;
  {
    int c = ln;
    int g = ln >> 4;
    float xw[4][7];
#pragma unroll
    for (int r = 0; r < 4; r++)
#pragma unroll
      for (int kx = 0; kx < 7; kx++) {
        int pos = r * 14 + w_ + kx;
        xw[r][kx] = xs[pos][XSW(c, pos)];
      }
#pragma unroll
    for (int ky = 0; ky < 7; ky++) {
      if (ky > 0) {
#pragma unroll
        for (int r = 0; r < 3; r++)
#pragma unroll
          for (int kx = 0; kx < 7; kx++) xw[r][kx] = xw[r + 1][kx];
#pragma unroll
        for (int kx = 0; kx < 7; kx++) {
          int pos = (ky + 3) * 14 + w_ + kx;
          xw[3][kx] = xs[pos][XSW(c, pos)];
        }
      }
#pragma unroll
      for (int kx = 0; kx < 7; kx++) {
        int k = ky * 7 + kx;
        float4 w4 = *(const float4*)&wvs[(g * 49 + k) * WVP4 + w_ * 4];
        acc0 = fmaf(w4.x, xw[0][kx], acc0);
        acc1 = fmaf(w4.y, xw[1][kx], acc1);
        acc2 = fmaf(w4.z, xw[2][kx], acc2);
        acc3 = fmaf(w4.w, xw[3][kx], acc3);
      }
    }
  }

  // ---- direct HWC store (outer ReLU fused)
  {
    int c = ln;
    int gx = ox0 + w_;
    if (gx < IW) {
      int base = (oy0 * IW + gx) * 64 + c;
      y[base]               = fmaxf(acc0, 0.f);
      y[base + 1 * IW * 64] = fmaxf(acc1, 0.f);
      if (oy0 + 2 < IH) y[base + 2 * IW * 64] = fmaxf(acc2, 0.f);
      if (oy0 + 3 < IH) y[base + 3 * IW * 64] = fmaxf(acc3, 0.f);
    }
  }
}

// ---------------------------------------------------------------- conv_out prep
// v9 layout: [k][grp4][wv4][cq16][ci4][oc8] — each (tap, wave) slab is 512
// CONTIGUOUS floats: inner-loop s_loads are base + immediate offsets.
__global__ __launch_bounds__(256) void transpose_w_kernel(
    const float* __restrict__ w, float* __restrict__ wt)
{
  int i = blockIdx.x * 256 + threadIdx.x;
  if (i >= 128 * 64 * 9) return;
  int oc = i / 576;
  int rem = i - oc * 576;
  int ci = rem / 9;
  int k = rem - ci * 9;
  int grp = oc >> 5, wv = (oc >> 3) & 3, oc8 = oc & 7;
  int cq = ci >> 2, ci4 = ci & 3;
  wt[(((k * 16 + grp * 4 + wv) * 16 + cq) * 4 + ci4) * 8 + oc8] = w[i];
}

// ---------------------------------------------------------------- conv_out v9 (FROZEN)
// ~42 us = scalar-cache-latency floor; 6 variants falsified every other
// mechanism (v3..v9 ladder). Do not touch.
__global__ __launch_bounds__(256, 6) void conv_out_kernel(
    const float* __restrict__ x, const float* __restrict__ wt,
    const float* __restrict__ b, float* __restrict__ y)
{
  __shared__ __align__(16) float xsm[16 * 100 * 4];   // 25,600 B
  int tid = threadIdx.x;
  int bx = blockIdx.x & 15, by = blockIdx.x >> 4;
  int oy0 = by * 8, ox0 = bx * 8;

  for (int u = tid; u < 1600; u += 256) {
    int cq = u / 100;
    int pos = u - cq * 100;
    int row = pos / 10;
    int col = pos - row * 10;
    int gy = oy0 + row, gx = ox0 + col;
    float4 v = make_float4(0.f, 0.f, 0.f, 0.f);
    if (gy < IH && gx < IW)
      v = *(const float4*)&x[(gy * IW + gx) * 64 + cq * 4];
    *(float4*)&xsm[u * 4] = v;
  }
  __syncthreads();

  int ln = tid & 63;
  int px = ln & 7, py = ln >> 3;
  int wv_ = __builtin_amdgcn_readfirstlane(tid >> 6);   // wave 0..3
  int oc8 = blockIdx.y * 32 + wv_ * 8;

  float acc[8];
#pragma unroll
  for (int j = 0; j < 8; j++) acc[j] = b[oc8 + j];

#pragma unroll
  for (int ky = 0; ky < 3; ky++) {
#pragma unroll
    for (int kx = 0; kx < 3; kx++) {
      int k = ky * 3 + kx;
      int pidx = (py + ky) * 10 + px + kx;
      // ONE uniform base per (tap, wave): 512 contiguous floats
      const float* wp = wt + (k * 16 + blockIdx.y * 4 + wv_) * 512;
#pragma unroll 4
      for (int cq = 0; cq < 16; cq++) {
        float4 xv = *(const float4*)&xsm[(cq * 100 + pidx) * 4];
        const float* wq = wp + cq * 32;         // imm offset: cq*128 B
#pragma unroll
        for (int j = 0; j < 8; j++) {
          acc[j] = fmaf(xv.x, wq[0 * 8 + j], acc[j]);
          acc[j] = fmaf(xv.y, wq[1 * 8 + j], acc[j]);
          acc[j] = fmaf(xv.z, wq[2 * 8 + j], acc[j]);
          acc[j] = fmaf(xv.w, wq[3 * 8 + j], acc[j]);
        }
      }
    }
  }

  int oy = oy0 + py, ox = ox0 + px;
  if (oy < OH && ox < OW) {
#pragma unroll
    for (int j = 0; j < 8; j++)
      y[(oc8 + j) * OHW + oy * OW + ox] = acc[j];
  }
}

// ---------------------------------------------------------------- launch
extern "C" void kernel_launch(void* const* d_in, const int* in_sizes, int n_in,
                              void* d_out, int out_size, void* d_ws, size_t ws_size,
                              hipStream_t stream)
{
  const float* input = (const float*)d_in[0];
  const float* ciw   = (const float*)d_in[1];
  const float* cib   = (const float*)d_in[2];
  const float* wred  = (const float*)d_in[3];
  const float* bred  = (const float*)d_in[4];
  const float* gam   = (const float*)d_in[5];
  const float* bet   = (const float*)d_in[6];
  const float* mu    = (const float*)d_in[7];
  const float* var   = (const float*)d_in[8];
  const float* wspan = (const float*)d_in[9];
  const float* bspan = (const float*)d_in[10];
  const float* cow   = (const float*)d_in[11];
  const float* cob   = (const float*)d_in[12];
  float* out = (float*)d_out;

  float* bufA = (float*)d_ws;                 // HWC: 15876*64 = 1,016,064 floats
  float* bufB = bufA + (1 << 20);             // @ 4 MiB
  float* wt   = bufA + (1 << 21);             // @ 8 MiB, 73,728 floats
  float* wt2  = wt + 73728;                   // 1,728 floats (conv_in weights)

  transpose_w_kernel<<<288, 256, 0, stream>>>(cow, wt);
  transpose_ci_kernel<<<7, 256, 0, stream>>>(ciw, wt2);
  conv_in_kernel<<<3969, 256, 0, stream>>>(input, wt2, cib, bufA);

  float* cur = bufA; float* nxt = bufB;
  for (int i = 0; i < 6; i++) {
    inv_kernel<<<512, 512, 0, stream>>>(cur, nxt,
        wred + i * 16 * 64, bred + i * 16, gam + i * 16, bet + i * 16,
        mu + i * 16, var + i * 16, wspan + i * 196 * 16, bspan + i * 196);
    float* t = cur; cur = nxt; nxt = t;
  }
  conv_out_kernel<<<dim3(256, 4), 256, 0, stream>>>(cur, wt, cob, out);
}